// Round 18
// baseline (8059.283 us; speedup 1.0000x reference)
//
#include <hip/hip_runtime.h>
#include <math.h>

// LSTMModel: 2048 sequential steps, 2x LSTMCell(H=512), LN(64) front, fc(512->1).
// R17 = R14/R16 base + LINE-GRANULAR polling (clean contention experiment):
// 32 pollers/block (was 128), each owning a full 64B line; L1 pollers cover their
// h0 AND h1 lines in ONE asm (8 loads, 1 waitcnt -> keeps R14's fused 1-RTT pair).
// Poll streams 24K -> 6K at identical bytes/round and identical hop count.
// If RTT is stream-contention-inflated -> step 2.43 -> ~1.9us. If parity -> the
// remaining cost is intrinsic MALL visibility+RTT; structural floor established.
// Ledger: scope games livelock (R3); deep polls regress via traffic (R12/R13);
// fan-out regresses (R13); layer-merge regresses (R10/R11); L1 in-wave exchange
// crosses the 48-float residency cliff (R15). Weights resident at 32/thread.

#define H      512
#define G4     2048
#define WIN    64
#define STEPS  2048
#define NL0B   64      // layer-0 blocks (8 units each)
#define NL1B   128     // layer-1 blocks (4 units each)
#define TPB    512
#define POISON 0xFFFFFFFFu

typedef unsigned int u32x4 __attribute__((ext_vector_type(4)));
typedef float        f32x4 __attribute__((ext_vector_type(4)));

__device__ __forceinline__ float sigf(float x)     { return 1.0f / (1.0f + __expf(-x)); }
__device__ __forceinline__ float tanhfast(float x) { return 2.0f / (1.0f + __expf(-2.0f * x)) - 1.0f; }

// ---- agent-scope helpers (issue+wait in ONE asm block -> sound) ----
__device__ __forceinline__ u32x4 ld4_sc01(const unsigned int* p) {
    u32x4 v;
    asm volatile("global_load_dwordx4 %0, %1, off sc0 sc1\n\ts_waitcnt vmcnt(0)"
                 : "=&v"(v) : "v"(p));
    return v;
}
// one 64B line (4 x4 packets), single waitcnt
__device__ __forceinline__ void ld16_sc01(const unsigned int* p, u32x4 (&r)[4]) {
    asm volatile("global_load_dwordx4 %0, %4, off sc0 sc1\n\t"
                 "global_load_dwordx4 %1, %4, off offset:16 sc0 sc1\n\t"
                 "global_load_dwordx4 %2, %4, off offset:32 sc0 sc1\n\t"
                 "global_load_dwordx4 %3, %4, off offset:48 sc0 sc1\n\t"
                 "s_waitcnt vmcnt(0)"
                 : "=&v"(r[0]), "=&v"(r[1]), "=&v"(r[2]), "=&v"(r[3])
                 : "v"(p));
}
// two 64B lines (h0 + h1) in flight together, single waitcnt -> 1 RTT for the pair
__device__ __forceinline__ void ld16x2_sc01(const unsigned int* pa, const unsigned int* pb,
                                            u32x4 (&a)[4], u32x4 (&b)[4]) {
    asm volatile("global_load_dwordx4 %0, %8, off sc0 sc1\n\t"
                 "global_load_dwordx4 %1, %8, off offset:16 sc0 sc1\n\t"
                 "global_load_dwordx4 %2, %8, off offset:32 sc0 sc1\n\t"
                 "global_load_dwordx4 %3, %8, off offset:48 sc0 sc1\n\t"
                 "global_load_dwordx4 %4, %9, off sc0 sc1\n\t"
                 "global_load_dwordx4 %5, %9, off offset:16 sc0 sc1\n\t"
                 "global_load_dwordx4 %6, %9, off offset:32 sc0 sc1\n\t"
                 "global_load_dwordx4 %7, %9, off offset:48 sc0 sc1\n\t"
                 "s_waitcnt vmcnt(0)"
                 : "=&v"(a[0]), "=&v"(a[1]), "=&v"(a[2]), "=&v"(a[3]),
                   "=&v"(b[0]), "=&v"(b[1]), "=&v"(b[2]), "=&v"(b[3])
                 : "v"(pa), "v"(pb));
}
__device__ __forceinline__ void st1_sc01(unsigned int* p, unsigned int v) {
    asm volatile("global_store_dword %0, %1, off sc0 sc1" :: "v"(p), "v"(v));
}
__device__ __forceinline__ void st4_sc01(unsigned int* p, u32x4 v) {
    asm volatile("global_store_dwordx4 %0, %1, off sc0 sc1" :: "v"(p), "v"(v));
}
__device__ __forceinline__ bool ok4(u32x4 v) {
    return v.x != POISON && v.y != POISON && v.z != POISON && v.w != POISON;
}
__device__ __forceinline__ bool ok16(const u32x4 (&r)[4]) {
    return ok4(r[0]) && ok4(r[1]) && ok4(r[2]) && ok4(r[3]);
}
__device__ __forceinline__ void lds_put4(float* dst, u32x4 v) {
    float4 f;
    f.x = __uint_as_float(v.x); f.y = __uint_as_float(v.y);
    f.z = __uint_as_float(v.z); f.w = __uint_as_float(v.w);
    *(float4*)dst = f;
}

// ---------------- LayerNorm over sliding windows (parallel over t) ----------------
__global__ void ln_kernel(const float* __restrict__ batch, const float* __restrict__ lnw,
                          const float* __restrict__ lnb, float* __restrict__ lnx) {
    int wave = threadIdx.x >> 6;
    int lane = threadIdx.x & 63;
    int t = blockIdx.x * 4 + wave;
    int src = t - 63 + lane;
    float v = (src >= 0) ? batch[src] : 0.0f;
    float s = v, ss = v * v;
    #pragma unroll
    for (int m = 32; m >= 1; m >>= 1) { s += __shfl_xor(s, m); ss += __shfl_xor(ss, m); }
    float mu   = s * (1.0f / 64.0f);
    float var  = ss * (1.0f / 64.0f) - mu * mu;
    float rstd = rsqrtf(var + 1e-5f);
    lnx[t * WIN + lane] = (v - mu) * rstd * lnw[lane] + lnb[lane];
}

// ---- precomp, UNIT-MAJOR layout: pre[t*2048 + unit*4 + gate] ----
__global__ __launch_bounds__(256) void precomp_kernel(
    const float* __restrict__ Wih0, const float* __restrict__ bih0,
    const float* __restrict__ bhh0, const float* __restrict__ lnx,
    float* __restrict__ pre) {
    __shared__ float Wt[64][65];
    __shared__ float Xt[64][64];
    int r0 = blockIdx.x * 64;
    int t0 = blockIdx.y * 64;
    for (int i = threadIdx.x; i < 4096; i += 256) Wt[i >> 6][i & 63] = Wih0[r0 * 64 + i];
    for (int i = threadIdx.x; i < 4096; i += 256) Xt[i >> 6][i & 63] = lnx[t0 * 64 + i];
    __syncthreads();
    int lane = threadIdx.x & 63;
    int wv   = threadIdx.x >> 6;
    int row  = r0 + lane;                      // gate-major: gate*512 + unit
    int oidx = (row & 511) * 4 + (row >> 9);   // unit-major: unit*4 + gate
    float bias = bih0[row] + bhh0[row];
    for (int j = 0; j < 16; ++j) {
        int tl = wv * 16 + j;
        float acc = bias;
        #pragma unroll 8
        for (int k = 0; k < 64; ++k) acc += Wt[lane][k] * Xt[tl][k];
        pre[(size_t)(t0 + tl) * G4 + oidx] = acc;
    }
}

// ---------------- persistent recurrent kernel ----------------
__global__ __launch_bounds__(TPB) void recur_kernel(
    const float* __restrict__ Whh0,
    const float* __restrict__ Wih1, const float* __restrict__ Whh1,
    const float* __restrict__ bih1, const float* __restrict__ bhh1,
    const float* __restrict__ pre,
    unsigned int* h0u, unsigned int* h1u) { // [STEPS+1][H] histories, NaN-poisoned
    const int tid = threadIdx.x;
    const int s   = tid & 31;
    const int LG  = tid >> 5;    // 16 lane-groups of 32

    if (blockIdx.x < NL0B) {
        // -------- layer-0: 8 units/block; unit = wave; 2 rows/lane-group --------
        __shared__ float hA[2][H];
        const int u0 = blockIdx.x * 8;
        const int u  = tid >> 6;              // wave index = unit-local
        float w0[2][16];
        #pragma unroll
        for (int j = 0; j < 2; ++j) {
            int r   = 2 * LG + j;
            int row = (r & 3) * H + u0 + (r >> 2);
            #pragma unroll
            for (int i = 0; i < 16; ++i) w0[j][i] = Whh0[(size_t)row * H + i * 32 + s];
        }
        float c0 = 0.0f;

        for (int t = 0; t < STEPS; ++t) {
            const int pb = t & 1;
            // pre for this wave's unit (wave-uniform broadcast load; hides under poll)
            f32x4 prv = *(const f32x4*)(pre + (size_t)t * G4 + (u0 + u) * 4);
            if (tid < 32) {
                if (t > 0) {
                    const unsigned int* p = h0u + (size_t)t * H + tid * 16;
                    u32x4 r[4];
                    do { ld16_sc01(p, r); } while (!ok16(r));
                    #pragma unroll
                    for (int k = 0; k < 4; ++k) lds_put4(&hA[pb][tid * 16 + k * 4], r[k]);
                } else {
                    #pragma unroll
                    for (int k = 0; k < 4; ++k)
                        *(float4*)&hA[pb][tid * 16 + k * 4] = make_float4(0.f, 0.f, 0.f, 0.f);
                }
            }
            __syncthreads();

            float acc0 = 0.0f, acc1 = 0.0f;
            #pragma unroll
            for (int i = 0; i < 16; ++i) {
                float hv = hA[pb][i * 32 + s];
                acc0 += w0[0][i] * hv;
                acc1 += w0[1][i] * hv;
            }
            #pragma unroll
            for (int m = 16; m >= 1; m >>= 1) {
                acc0 += __shfl_xor(acc0, m);
                acc1 += __shfl_xor(acc1, m);
            }
            // lower half-wave group: gates i,f ; upper (lane 32): g,o
            float gacc = __shfl(acc0, 32);
            float oacc = __shfl(acc1, 32);
            if ((tid & 63) == 0) {
                float iv = sigf(acc0 + prv.x);
                float fv = sigf(acc1 + prv.y);
                float gv = tanhfast(gacc + prv.z);
                float ov = sigf(oacc + prv.w);
                c0 = fv * c0 + iv * gv;
                float hnew = ov * tanhfast(c0);
                st1_sc01(h0u + (size_t)(t + 1) * H + u0 + u, __float_as_uint(hnew));
            }
        }
    } else {
        // -------- layer-1: 4 units/block; 1 row/lane-group; LDS gate exchange --------
        __shared__ float hA2[2][H];
        __shared__ float hB2[2][H];
        __shared__ float glds[16];
        const int b1 = blockIdx.x - NL0B;
        const int u0 = b1 * 4;
        const int row = (LG & 3) * H + u0 + (LG >> 2);
        float w1[16], w2[16];
        #pragma unroll
        for (int i = 0; i < 16; ++i) {
            w1[i] = Wih1[(size_t)row * H + i * 32 + s];
            w2[i] = Whh1[(size_t)row * H + i * 32 + s];
        }
        const float rbias = bih1[row] + bhh1[row];
        float c1 = 0.0f;

        for (int t = 0; t < STEPS; ++t) {
            const int pb = t & 1;
            if (tid < 32) {
                const unsigned int* pa = h0u + (size_t)(t + 1) * H + tid * 16;
                if (t > 0) {
                    // DUAL-LINE poll: h0 feed + h1 self-chain in one asm, one wait
                    const unsigned int* pbp = h1u + (size_t)t * H + tid * 16;
                    u32x4 a[4], b[4];
                    do { ld16x2_sc01(pa, pbp, a, b); } while (!(ok16(a) && ok16(b)));
                    #pragma unroll
                    for (int k = 0; k < 4; ++k) {
                        lds_put4(&hA2[pb][tid * 16 + k * 4], a[k]);
                        lds_put4(&hB2[pb][tid * 16 + k * 4], b[k]);
                    }
                } else {
                    u32x4 a[4];
                    do { ld16_sc01(pa, a); } while (!ok16(a));
                    #pragma unroll
                    for (int k = 0; k < 4; ++k) {
                        lds_put4(&hA2[pb][tid * 16 + k * 4], a[k]);
                        *(float4*)&hB2[pb][tid * 16 + k * 4] = make_float4(0.f, 0.f, 0.f, 0.f);
                    }
                }
            }
            __syncthreads();

            float acc = 0.0f;
            #pragma unroll
            for (int i = 0; i < 16; ++i)
                acc += w1[i] * hA2[pb][i * 32 + s] + w2[i] * hB2[pb][i * 32 + s];
            #pragma unroll
            for (int m = 16; m >= 1; m >>= 1) acc += __shfl_xor(acc, m);
            if (s == 0) glds[LG] = acc + rbias;
            __syncthreads();

            float hnew = 0.0f;
            if (tid < 4) {
                float iv = sigf(glds[4 * tid + 0]);
                float fv = sigf(glds[4 * tid + 1]);
                float gv = tanhfast(glds[4 * tid + 2]);
                float ov = sigf(glds[4 * tid + 3]);
                c1 = fv * c1 + iv * gv;
                hnew = ov * tanhfast(c1);
            }
            // atomic packed publish: lanes 0-3 (wave 0) gathered into one st4
            if (tid < 64) {
                unsigned int hb = __float_as_uint(hnew);
                u32x4 pk;
                pk.x = __shfl(hb, 0); pk.y = __shfl(hb, 1);
                pk.z = __shfl(hb, 2); pk.w = __shfl(hb, 3);
                if (tid == 0)
                    st4_sc01(h1u + (size_t)(t + 1) * H + u0, pk);
            }
        }
    }
}

// ---------------- out[t] = fc(relu(h1[t+1])) from the h1 history ----------------
__global__ __launch_bounds__(TPB) void reduce_out(
    const unsigned int* __restrict__ h1u, const float* __restrict__ fcw,
    const float* __restrict__ fcb, float* __restrict__ out) {
    int t = blockIdx.x;
    int tid = threadIdx.x;               // 512 threads
    float h = __uint_as_float(h1u[(size_t)(t + 1) * H + tid]);
    float v = fmaxf(h, 0.0f) * fcw[tid];
    #pragma unroll
    for (int m = 32; m >= 1; m >>= 1) v += __shfl_xor(v, m);
    __shared__ float ws8[8];
    if ((tid & 63) == 0) ws8[tid >> 6] = v;
    __syncthreads();
    if (tid == 0) {
        float ssum = 0.0f;
        #pragma unroll
        for (int i = 0; i < 8; ++i) ssum += ws8[i];
        out[t] = ssum + fcb[0];
    }
}

extern "C" void kernel_launch(void* const* d_in, const int* in_sizes, int n_in,
                              void* d_out, int out_size, void* d_ws, size_t ws_size,
                              hipStream_t stream) {
    const float* batch = (const float*)d_in[0];
    const float* Wih0  = (const float*)d_in[1];
    const float* Whh0  = (const float*)d_in[2];
    const float* bih0  = (const float*)d_in[3];
    const float* bhh0  = (const float*)d_in[4];
    const float* Wih1  = (const float*)d_in[5];
    const float* Whh1  = (const float*)d_in[6];
    const float* bih1  = (const float*)d_in[7];
    const float* bhh1  = (const float*)d_in[8];
    const float* lnw   = (const float*)d_in[9];
    const float* lnb   = (const float*)d_in[10];
    const float* fcw   = (const float*)d_in[11];
    const float* fcb   = (const float*)d_in[12];
    float* out = (float*)d_out;

    // workspace layout (~17 MB)
    float*        ws   = (float*)d_ws;
    float*        pre  = ws;                                   // 2048*2048 (16 MB)
    float*        lnx  = pre + (size_t)STEPS * G4;             // 2048*64
    unsigned int* h0u  = (unsigned int*)(lnx + (size_t)STEPS * WIN);  // 2049*512
    unsigned int* h1u  = h0u + (size_t)(STEPS + 1) * H;        // 2049*512

    // poison both h histories (NaN pattern); slot 0 handled by t==0 branch in-kernel
    (void)hipMemsetAsync(h0u, 0xFF, (size_t)2 * (STEPS + 1) * H * sizeof(unsigned int), stream);

    ln_kernel<<<dim3(STEPS / 4), dim3(256), 0, stream>>>(batch, lnw, lnb, lnx);
    precomp_kernel<<<dim3(G4 / 64, STEPS / 64), dim3(256), 0, stream>>>(Wih0, bih0, bhh0, lnx, pre);
    recur_kernel<<<dim3(NL0B + NL1B), dim3(TPB), 0, stream>>>(Whh0, Wih1, Whh1, bih1, bhh1,
                                                              pre, h0u, h1u);
    reduce_out<<<dim3(STEPS), dim3(TPB), 0, stream>>>(h1u, fcw, fcb, out);
}

// Round 19
// 4994.575 us; speedup vs baseline: 1.6136x; 1.6136x over previous
//
#include <hip/hip_runtime.h>
#include <math.h>

// LSTMModel: 2048 sequential steps, 2x LSTMCell(H=512), LN(64) front, fc(512->1).
// R18 = REVERT to R14 (proven best: 4.996ms), the structural optimum found over
// 17 rounds. Step = 2.42us = agent-scope store-visibility + MALL poll RTT +
// 128-publisher straggler + 1 barrier + ~0.3us compute, x2048 serial hops.
// Complete ledger:
//  - data-as-flag NaN-poison polling beats counters/barriers (R2).
//  - weights MUST be <=48 f32/thread to stay register-resident (R10/R15 bracket);
//    KEEP()/pins cannot force residency (R6-R8).
//  - L1's h0+h1 polls fused in ONE asm with one vmcnt(0) -> 1 RTT/check (R14, -16%).
//  - REGRESS: sc0 scope games (livelock, R3), pipelined/deep polls (R12/R13),
//    mailbox fan-out (R13), layer-merge (R10/R11), line-granular polls (R17),
//    direct-tap 16-word polls (R7), async reg-held prefetch (R8 unsound).
// Split issue/wait across asm statements is UNSOUND (regalloc copies in-flight
// dest regs) -- issue+wait must live in ONE asm block.

#define H      512
#define G4     2048
#define WIN    64
#define STEPS  2048
#define NL0B   64      // layer-0 blocks (8 units each)
#define NL1B   128     // layer-1 blocks (4 units each)
#define TPB    512
#define POISON 0xFFFFFFFFu

typedef unsigned int u32x4 __attribute__((ext_vector_type(4)));
typedef float        f32x4 __attribute__((ext_vector_type(4)));

__device__ __forceinline__ float sigf(float x)     { return 1.0f / (1.0f + __expf(-x)); }
__device__ __forceinline__ float tanhfast(float x) { return 2.0f / (1.0f + __expf(-2.0f * x)) - 1.0f; }

// ---- agent-scope helpers (issue+wait in ONE asm block -> sound) ----
__device__ __forceinline__ u32x4 ld4_sc01(const unsigned int* p) {
    u32x4 v;
    asm volatile("global_load_dwordx4 %0, %1, off sc0 sc1\n\ts_waitcnt vmcnt(0)"
                 : "=&v"(v) : "v"(p));
    return v;
}
// dual-packet load: both in flight together, one wait -> 1 RTT for the pair
__device__ __forceinline__ void ld4x2_sc01(const unsigned int* pa, const unsigned int* pb,
                                           u32x4& va, u32x4& vb) {
    asm volatile("global_load_dwordx4 %0, %2, off sc0 sc1\n\t"
                 "global_load_dwordx4 %1, %3, off sc0 sc1\n\t"
                 "s_waitcnt vmcnt(0)"
                 : "=&v"(va), "=&v"(vb) : "v"(pa), "v"(pb));
}
__device__ __forceinline__ void st1_sc01(unsigned int* p, unsigned int v) {
    asm volatile("global_store_dword %0, %1, off sc0 sc1" :: "v"(p), "v"(v));
}
__device__ __forceinline__ bool ok4(u32x4 v) {
    return v.x != POISON && v.y != POISON && v.z != POISON && v.w != POISON;
}
__device__ __forceinline__ void lds_put4(float* dst, u32x4 v) {
    float4 f;
    f.x = __uint_as_float(v.x); f.y = __uint_as_float(v.y);
    f.z = __uint_as_float(v.z); f.w = __uint_as_float(v.w);
    *(float4*)dst = f;
}

// ---------------- LayerNorm over sliding windows (parallel over t) ----------------
__global__ void ln_kernel(const float* __restrict__ batch, const float* __restrict__ lnw,
                          const float* __restrict__ lnb, float* __restrict__ lnx) {
    int wave = threadIdx.x >> 6;
    int lane = threadIdx.x & 63;
    int t = blockIdx.x * 4 + wave;
    int src = t - 63 + lane;
    float v = (src >= 0) ? batch[src] : 0.0f;
    float s = v, ss = v * v;
    #pragma unroll
    for (int m = 32; m >= 1; m >>= 1) { s += __shfl_xor(s, m); ss += __shfl_xor(ss, m); }
    float mu   = s * (1.0f / 64.0f);
    float var  = ss * (1.0f / 64.0f) - mu * mu;
    float rstd = rsqrtf(var + 1e-5f);
    lnx[t * WIN + lane] = (v - mu) * rstd * lnw[lane] + lnb[lane];
}

// ---- precomp, UNIT-MAJOR layout: pre[t*2048 + unit*4 + gate] ----
__global__ __launch_bounds__(256) void precomp_kernel(
    const float* __restrict__ Wih0, const float* __restrict__ bih0,
    const float* __restrict__ bhh0, const float* __restrict__ lnx,
    float* __restrict__ pre) {
    __shared__ float Wt[64][65];
    __shared__ float Xt[64][64];
    int r0 = blockIdx.x * 64;
    int t0 = blockIdx.y * 64;
    for (int i = threadIdx.x; i < 4096; i += 256) Wt[i >> 6][i & 63] = Wih0[r0 * 64 + i];
    for (int i = threadIdx.x; i < 4096; i += 256) Xt[i >> 6][i & 63] = lnx[t0 * 64 + i];
    __syncthreads();
    int lane = threadIdx.x & 63;
    int wv   = threadIdx.x >> 6;
    int row  = r0 + lane;                      // gate-major: gate*512 + unit
    int oidx = (row & 511) * 4 + (row >> 9);   // unit-major: unit*4 + gate
    float bias = bih0[row] + bhh0[row];
    for (int j = 0; j < 16; ++j) {
        int tl = wv * 16 + j;
        float acc = bias;
        #pragma unroll 8
        for (int k = 0; k < 64; ++k) acc += Wt[lane][k] * Xt[tl][k];
        pre[(size_t)(t0 + tl) * G4 + oidx] = acc;
    }
}

// ---------------- persistent recurrent kernel ----------------
__global__ __launch_bounds__(TPB) void recur_kernel(
    const float* __restrict__ Whh0,
    const float* __restrict__ Wih1, const float* __restrict__ Whh1,
    const float* __restrict__ bih1, const float* __restrict__ bhh1,
    const float* __restrict__ pre,
    unsigned int* h0u, unsigned int* h1u) { // [STEPS+1][H] histories, NaN-poisoned
    const int tid = threadIdx.x;
    const int s   = tid & 31;
    const int LG  = tid >> 5;    // 16 lane-groups of 32

    if (blockIdx.x < NL0B) {
        // -------- layer-0: 8 units/block; unit = wave; 2 rows/lane-group --------
        __shared__ float hA[2][H];
        const int u0 = blockIdx.x * 8;
        const int u  = tid >> 6;              // wave index = unit-local
        float w0[2][16];
        #pragma unroll
        for (int j = 0; j < 2; ++j) {
            int r   = 2 * LG + j;
            int row = (r & 3) * H + u0 + (r >> 2);
            #pragma unroll
            for (int i = 0; i < 16; ++i) w0[j][i] = Whh0[(size_t)row * H + i * 32 + s];
        }
        float c0 = 0.0f;

        for (int t = 0; t < STEPS; ++t) {
            const int pb = t & 1;
            // pre for this wave's unit (wave-uniform broadcast load; hides under poll)
            f32x4 prv = *(const f32x4*)(pre + (size_t)t * G4 + (u0 + u) * 4);
            if (tid < 128) {
                if (t > 0) {
                    const unsigned int* p = h0u + (size_t)t * H + tid * 4;
                    u32x4 v;
                    do { v = ld4_sc01(p); } while (!ok4(v));
                    lds_put4(&hA[pb][tid * 4], v);
                } else {
                    *(float4*)&hA[pb][tid * 4] = make_float4(0.f, 0.f, 0.f, 0.f);
                }
            }
            __syncthreads();

            float acc0 = 0.0f, acc1 = 0.0f;
            #pragma unroll
            for (int i = 0; i < 16; ++i) {
                float hv = hA[pb][i * 32 + s];
                acc0 += w0[0][i] * hv;
                acc1 += w0[1][i] * hv;
            }
            #pragma unroll
            for (int m = 16; m >= 1; m >>= 1) {
                acc0 += __shfl_xor(acc0, m);
                acc1 += __shfl_xor(acc1, m);
            }
            // lower half-wave group: gates i,f ; upper (lane 32): g,o
            float gacc = __shfl(acc0, 32);
            float oacc = __shfl(acc1, 32);
            if ((tid & 63) == 0) {
                float iv = sigf(acc0 + prv.x);
                float fv = sigf(acc1 + prv.y);
                float gv = tanhfast(gacc + prv.z);
                float ov = sigf(oacc + prv.w);
                c0 = fv * c0 + iv * gv;
                float hnew = ov * tanhfast(c0);
                st1_sc01(h0u + (size_t)(t + 1) * H + u0 + u, __float_as_uint(hnew));
            }
        }
    } else {
        // -------- layer-1: 4 units/block; 1 row/lane-group; LDS gate exchange --------
        __shared__ float hA2[2][H];
        __shared__ float hB2[2][H];
        __shared__ float glds[16];
        const int b1 = blockIdx.x - NL0B;
        const int u0 = b1 * 4;
        const int row = (LG & 3) * H + u0 + (LG >> 2);
        float w1[16], w2[16];
        #pragma unroll
        for (int i = 0; i < 16; ++i) {
            w1[i] = Wih1[(size_t)row * H + i * 32 + s];
            w2[i] = Whh1[(size_t)row * H + i * 32 + s];
        }
        const float rbias = bih1[row] + bhh1[row];
        float c1 = 0.0f;

        for (int t = 0; t < STEPS; ++t) {
            const int pb = t & 1;
            if (tid < 128) {
                const unsigned int* pa = h0u + (size_t)(t + 1) * H + tid * 4;
                if (t > 0) {
                    // DUAL poll: h0 feed + h1 self-chain in flight together, one wait
                    const unsigned int* pbp = h1u + (size_t)t * H + tid * 4;
                    u32x4 va, vb;
                    do { ld4x2_sc01(pa, pbp, va, vb); } while (!(ok4(va) && ok4(vb)));
                    lds_put4(&hA2[pb][tid * 4], va);
                    lds_put4(&hB2[pb][tid * 4], vb);
                } else {
                    u32x4 va;
                    do { va = ld4_sc01(pa); } while (!ok4(va));
                    lds_put4(&hA2[pb][tid * 4], va);
                    *(float4*)&hB2[pb][tid * 4] = make_float4(0.f, 0.f, 0.f, 0.f);
                }
            }
            __syncthreads();

            float acc = 0.0f;
            #pragma unroll
            for (int i = 0; i < 16; ++i)
                acc += w1[i] * hA2[pb][i * 32 + s] + w2[i] * hB2[pb][i * 32 + s];
            #pragma unroll
            for (int m = 16; m >= 1; m >>= 1) acc += __shfl_xor(acc, m);
            if (s == 0) glds[LG] = acc + rbias;
            __syncthreads();
            if (tid < 4) {
                float iv = sigf(glds[4 * tid + 0]);
                float fv = sigf(glds[4 * tid + 1]);
                float gv = tanhfast(glds[4 * tid + 2]);
                float ov = sigf(glds[4 * tid + 3]);
                c1 = fv * c1 + iv * gv;
                float hnew = ov * tanhfast(c1);
                st1_sc01(h1u + (size_t)(t + 1) * H + u0 + tid, __float_as_uint(hnew));
            }
        }
    }
}

// ---------------- out[t] = fc(relu(h1[t+1])) from the h1 history ----------------
__global__ __launch_bounds__(TPB) void reduce_out(
    const unsigned int* __restrict__ h1u, const float* __restrict__ fcw,
    const float* __restrict__ fcb, float* __restrict__ out) {
    int t = blockIdx.x;
    int tid = threadIdx.x;               // 512 threads
    float h = __uint_as_float(h1u[(size_t)(t + 1) * H + tid]);
    float v = fmaxf(h, 0.0f) * fcw[tid];
    #pragma unroll
    for (int m = 32; m >= 1; m >>= 1) v += __shfl_xor(v, m);
    __shared__ float ws8[8];
    if ((tid & 63) == 0) ws8[tid >> 6] = v;
    __syncthreads();
    if (tid == 0) {
        float ssum = 0.0f;
        #pragma unroll
        for (int i = 0; i < 8; ++i) ssum += ws8[i];
        out[t] = ssum + fcb[0];
    }
}

extern "C" void kernel_launch(void* const* d_in, const int* in_sizes, int n_in,
                              void* d_out, int out_size, void* d_ws, size_t ws_size,
                              hipStream_t stream) {
    const float* batch = (const float*)d_in[0];
    const float* Wih0  = (const float*)d_in[1];
    const float* Whh0  = (const float*)d_in[2];
    const float* bih0  = (const float*)d_in[3];
    const float* bhh0  = (const float*)d_in[4];
    const float* Wih1  = (const float*)d_in[5];
    const float* Whh1  = (const float*)d_in[6];
    const float* bih1  = (const float*)d_in[7];
    const float* bhh1  = (const float*)d_in[8];
    const float* lnw   = (const float*)d_in[9];
    const float* lnb   = (const float*)d_in[10];
    const float* fcw   = (const float*)d_in[11];
    const float* fcb   = (const float*)d_in[12];
    float* out = (float*)d_out;

    // workspace layout (~17 MB)
    float*        ws   = (float*)d_ws;
    float*        pre  = ws;                                   // 2048*2048 (16 MB)
    float*        lnx  = pre + (size_t)STEPS * G4;             // 2048*64
    unsigned int* h0u  = (unsigned int*)(lnx + (size_t)STEPS * WIN);  // 2049*512
    unsigned int* h1u  = h0u + (size_t)(STEPS + 1) * H;        // 2049*512

    // poison both h histories (NaN pattern); slot 0 handled by t==0 branch in-kernel
    (void)hipMemsetAsync(h0u, 0xFF, (size_t)2 * (STEPS + 1) * H * sizeof(unsigned int), stream);

    ln_kernel<<<dim3(STEPS / 4), dim3(256), 0, stream>>>(batch, lnw, lnb, lnx);
    precomp_kernel<<<dim3(G4 / 64, STEPS / 64), dim3(256), 0, stream>>>(Wih0, bih0, bhh0, lnx, pre);
    recur_kernel<<<dim3(NL0B + NL1B), dim3(TPB), 0, stream>>>(Whh0, Wih1, Whh1, bih1, bhh1,
                                                              pre, h0u, h1u);
    reduce_out<<<dim3(STEPS), dim3(TPB), 0, stream>>>(h1u, fcw, fcb, out);
}